// Round 2
// baseline (504.717 us; speedup 1.0000x reference)
//
#include <hip/hip_runtime.h>
#include <hip/hip_bf16.h>

// Fused edge-MLP: out = prelu(prelu([x_i|x_j|ea] @ W1 + b1) @ W2 + b2)
// E=500000, H=1, C=64, CE=16, HID=128, d_in=144. fp32 in/out; bf16 MFMA inside.
// Round 2: register double-buffered tile prefetch (latency-bound fix),
// b2 folded into acc2 init, conflict-free LDS strides, NaN-safe pad.

#define E_ROWS 500000
#define TILES  15625          // E_ROWS / 32
#define NBLK   512
#define NWAVES (NBLK * 4)     // 2048 waves, grid-stride over tiles

#define LDW1 152              // stride 76 dw: 12r mod 32 -> uniform over 4-bank groups (conflict-free b128)
#define LDW2 136              // stride 68 dw: 4r mod 32  -> uniform (conflict-free b128)

typedef short  bf8_t  __attribute__((ext_vector_type(8)));   // 8 x bf16 bits
typedef float  f32x16 __attribute__((ext_vector_type(16)));

static __device__ __forceinline__ short f2bf(float v) {
    return (short)__builtin_bit_cast(unsigned short, __float2bfloat16(v));
}

__global__ __launch_bounds__(256, 2)
void message_pass_kernel(const float* __restrict__ x_i,
                         const float* __restrict__ x_j,
                         const float* __restrict__ ea,
                         const float* __restrict__ W1,
                         const float* __restrict__ b1,
                         const float* __restrict__ W2,
                         const float* __restrict__ b2,
                         const float* __restrict__ alpha_p,
                         float* __restrict__ out)
{
    // W1T: row i = HID idx (128), col k: 0..143 = W1[k][i], 144 = b1[i], 145..151 = 0.
    // +16 pad zeroed: the bias-step g2=1 read touches cols 152..159 of the last row;
    // garbage there multiplies a zero b-slot, but must be finite (NaN*0=NaN in MFMA).
    __shared__ __align__(16) short sW1[128 * LDW1 + 16];
    // W2R: row n = out col (64), col c holds W2[k][n] with k = c bits2<->3 swapped; k>=128 -> 0.
    __shared__ __align__(16) short sW2[64 * LDW2];

    const int tid = threadIdx.x;

    for (int idx = tid; idx < 128 * LDW1; idx += 256) {
        int i = idx & 127, c = idx >> 7;             // coalesced over i
        float v = 0.f;
        if (c < 144)       v = W1[c * 128 + i];
        else if (c == 144) v = b1[i];
        sW1[i * LDW1 + c] = f2bf(v);
    }
    if (tid < 16) sW1[128 * LDW1 + tid] = 0;
    for (int idx = tid; idx < 64 * LDW2; idx += 256) {
        int i = idx & 63, c = idx >> 6;              // c in 0..135
        int k = (c & ~12) | ((c & 4) << 1) | ((c & 8) >> 1);  // swap bits 2<->3
        float v = (k < 128) ? W2[k * 64 + i] : 0.f;
        sW2[i * LDW2 + c] = f2bf(v);
    }
    __syncthreads();

    const float alpha = alpha_p[0];
    const int lane = tid & 63;
    const int l31  = lane & 31;
    const int g2   = lane >> 5;
    const int wv   = blockIdx.x * 4 + (tid >> 6);

    // Layer-2 bias: C-layout col n = 32*t2 + l31 is lane-uniform across regs -> init acc2 with it.
    const float bias2_0 = b2[l31];
    const float bias2_1 = b2[32 + l31];

    auto load_tile = [&](float4 (&ld)[9][2], int T) {
        const size_t row0 = (size_t)T * 32;
        const float* xi = x_i + (row0 + l31) * 64 + 8 * g2;
        const float* xj = x_j + (row0 + l31) * 64 + 8 * g2;
        const float* er = ea  + (row0 + l31) * 16 + 8 * g2;
        #pragma unroll
        for (int s = 0; s < 4; ++s) {
            ld[s][0]     = *(const float4*)(xi + 16 * s);
            ld[s][1]     = *(const float4*)(xi + 16 * s + 4);
            ld[4 + s][0] = *(const float4*)(xj + 16 * s);
            ld[4 + s][1] = *(const float4*)(xj + 16 * s + 4);
        }
        ld[8][0] = *(const float4*)(er);
        ld[8][1] = *(const float4*)(er + 4);
    };

    auto compute_tile = [&](const float4 (&ld)[9][2], int T) {
        const size_t row0 = (size_t)T * 32;

        // ---- layer 1 (swapped): H^T = W1^T * concat^T; K = 144 + bias step ----
        f32x16 acc[4] = {};
        #pragma unroll
        for (int s = 0; s < 9; ++s) {
            bf8_t b;
            b[0] = f2bf(ld[s][0].x); b[1] = f2bf(ld[s][0].y);
            b[2] = f2bf(ld[s][0].z); b[3] = f2bf(ld[s][0].w);
            b[4] = f2bf(ld[s][1].x); b[5] = f2bf(ld[s][1].y);
            b[6] = f2bf(ld[s][1].z); b[7] = f2bf(ld[s][1].w);
            #pragma unroll
            for (int t1 = 0; t1 < 4; ++t1) {
                const bf8_t a = *(const bf8_t*)(sW1 + (32 * t1 + l31) * LDW1 + 16 * s + 8 * g2);
                acc[t1] = __builtin_amdgcn_mfma_f32_32x32x16_bf16(a, b, acc[t1], 0, 0, 0);
            }
        }
        {   // bias K-step: concat col 144 == 1.0 (only slot (g2=0,e=0) nonzero)
            bf8_t b = {};
            b[0] = (short)(g2 == 0 ? 0x3F80 : 0);
            #pragma unroll
            for (int t1 = 0; t1 < 4; ++t1) {
                const bf8_t a = *(const bf8_t*)(sW1 + (32 * t1 + l31) * LDW1 + 144 + 8 * g2);
                acc[t1] = __builtin_amdgcn_mfma_f32_32x32x16_bf16(a, b, acc[t1], 0, 0, 0);
            }
        }

        // ---- layer 2: out = prelu(H) * W2 + b2; K = 128, A is lane-local acc regs ----
        f32x16 acc2[2];
        #pragma unroll
        for (int r = 0; r < 16; ++r) { acc2[0][r] = bias2_0; acc2[1][r] = bias2_1; }
        #pragma unroll
        for (int s = 0; s < 8; ++s) {
            const int t = s >> 1, rb = (s & 1) * 8;
            bf8_t a;
            #pragma unroll
            for (int e = 0; e < 8; ++e) {
                float v = acc[t][rb + e];
                v = fmaxf(v, 0.f) + alpha * fminf(v, 0.f);   // PReLU
                a[e] = f2bf(v);
            }
            #pragma unroll
            for (int t2 = 0; t2 < 2; ++t2) {
                const bf8_t bb = *(const bf8_t*)(sW2 + (32 * t2 + l31) * LDW2 + 16 * s + 8 * g2);
                acc2[t2] = __builtin_amdgcn_mfma_f32_32x32x16_bf16(a, bb, acc2[t2], 0, 0, 0);
            }
        }

        // ---- PReLU + store: lane holds out[row0 + m][32*t2 + l31], m=(r&3)+8*(r>>2)+4*g2 ----
        float* op = out + row0 * 64;
        #pragma unroll
        for (int t2 = 0; t2 < 2; ++t2) {
            #pragma unroll
            for (int r = 0; r < 16; ++r) {
                const int m = (r & 3) + 8 * (r >> 2) + 4 * g2;
                float v = acc2[t2][r];
                v = fmaxf(v, 0.f) + alpha * fminf(v, 0.f);
                op[(size_t)m * 64 + 32 * t2 + l31] = v;
            }
        }
    };

    // ---- software pipeline: prefetch tile T+NWAVES while computing tile T ----
    float4 bufA[9][2], bufB[9][2];
    int T = wv;                       // wv < 2048 <= TILES, always valid
    load_tile(bufA, T);
    for (;;) {
        int T1 = T + NWAVES;
        if (T1 >= TILES) { compute_tile(bufA, T); break; }
        load_tile(bufB, T1);
        compute_tile(bufA, T);
        int T2 = T1 + NWAVES;
        if (T2 >= TILES) { compute_tile(bufB, T1); break; }
        load_tile(bufA, T2);
        compute_tile(bufB, T1);
        T = T2;
    }
}

extern "C" void kernel_launch(void* const* d_in, const int* in_sizes, int n_in,
                              void* d_out, int out_size, void* d_ws, size_t ws_size,
                              hipStream_t stream) {
    const float* x_i  = (const float*)d_in[0];
    const float* x_j  = (const float*)d_in[1];
    const float* ea   = (const float*)d_in[2];
    const float* W1   = (const float*)d_in[3];
    const float* b1   = (const float*)d_in[4];
    const float* W2   = (const float*)d_in[5];
    const float* b2   = (const float*)d_in[6];
    const float* alph = (const float*)d_in[7];
    message_pass_kernel<<<NBLK, 256, 0, stream>>>(x_i, x_j, ea, W1, b1, W2, b2, alph,
                                                  (float*)d_out);
}